// Round 6
// baseline (211.893 us; speedup 1.0000x reference)
//
#include <hip/hip_runtime.h>
#include <hip/hip_bf16.h>

typedef __attribute__((ext_vector_type(8))) short bf16x8;
typedef __attribute__((ext_vector_type(4))) float f32x4;

#define MFMA16(a, b, c) __builtin_amdgcn_mfma_f32_16x16x32_bf16(a, b, c, 0, 0, 0)

static constexpr int Bn = 2;
static constexpr int S  = 4096;   // H*W
static constexpr int C  = 512;
static constexpr int NH = 8;
static constexpr int HD = 64;
static constexpr int M  = Bn * S; // 8192
static constexpr int NROWS = Bn * NH * S;  // 65536 (b,h,q) rows

// q pre-scale: hd^-1/2 * log2(e)  (softmax computed in base-2 domain)
#define QSCALE 0.18033688f
#define DEFER_THR 11.0f

__device__ __forceinline__ ushort f2bf(float f) {
  unsigned u = __builtin_bit_cast(unsigned, f);
  u += 0x7fffu + ((u >> 16) & 1u);
  return (ushort)(u >> 16);
}

__device__ __forceinline__ unsigned pkbf(float a, float b) {
  return (unsigned)f2bf(a) | ((unsigned)f2bf(b) << 16);
}

// hardware packed f32->bf16 (RNE), lo=a hi=b
__device__ __forceinline__ unsigned cvtpk(float a, float b) {
  unsigned r;
  asm("v_cvt_pk_bf16_f32 %0, %1, %2" : "=v"(r) : "v"(a), "v"(b));
  return r;
}

#define GLOAD_LDS16(g, l) __builtin_amdgcn_global_load_lds( \
    (const __attribute__((address_space(1))) unsigned*)(const void*)(g), \
    (__attribute__((address_space(3))) unsigned*)(void*)(l), 16, 0, 0)

// ---------------- GroupNorm stats: one block per (b, group) ----------------
__global__ __launch_bounds__(256) void gn_stats_kernel(const float* __restrict__ x,
                                                       float2* __restrict__ stats) {
  int bg = blockIdx.x;            // 0..63
  int b = bg >> 5, g = bg & 31;
  const float* xp = x + (size_t)b * S * C + g * 16;
  float sum = 0.f, sq = 0.f;
  for (int s = threadIdx.x; s < S; s += 256) {
    const float4* p = (const float4*)(xp + (size_t)s * C);
    #pragma unroll
    for (int i = 0; i < 4; i++) {
      float4 v = p[i];
      sum += v.x + v.y + v.z + v.w;
      sq  += v.x * v.x + v.y * v.y + v.z * v.z + v.w * v.w;
    }
  }
  #pragma unroll
  for (int d = 1; d < 64; d <<= 1) {
    sum += __shfl_xor(sum, d);
    sq  += __shfl_xor(sq, d);
  }
  __shared__ float2 red[4];
  if ((threadIdx.x & 63) == 0) red[threadIdx.x >> 6] = make_float2(sum, sq);
  __syncthreads();
  if (threadIdx.x == 0) {
    float s0 = 0.f, q0 = 0.f;
    #pragma unroll
    for (int i = 0; i < 4; i++) { s0 += red[i].x; q0 += red[i].y; }
    float inv = 1.f / (float)(S * 16);
    float mean = s0 * inv;
    float var = q0 * inv - mean * mean;
    stats[bg] = make_float2(mean, rsqrtf(var + 1e-6f));
  }
}

// ---------------- GroupNorm apply + cast to bf16 ----------------
__global__ __launch_bounds__(256) void gn_apply_kernel(const float* __restrict__ x,
                                                       const float* __restrict__ sc,
                                                       const float* __restrict__ bi,
                                                       const float2* __restrict__ stats,
                                                       ushort* __restrict__ h) {
  int i = blockIdx.x * 256 + threadIdx.x;   // 0..524287, 8 channels each
  int s = i >> 6;
  int c0 = (i & 63) << 3;
  int b = s >> 12;
  float2 st = stats[(b << 5) + (c0 >> 4)];
  const float4* xv = (const float4*)(x + (size_t)s * C + c0);
  const float4* sv = (const float4*)(sc + c0);
  const float4* bv = (const float4*)(bi + c0);
  float4 a0 = xv[0], a1 = xv[1];
  float4 s0 = sv[0], s1 = sv[1];
  float4 b0 = bv[0], b1 = bv[1];
  uint4 pk;
  pk.x = pkbf((a0.x - st.x) * st.y * s0.x + b0.x, (a0.y - st.x) * st.y * s0.y + b0.y);
  pk.y = pkbf((a0.z - st.x) * st.y * s0.z + b0.z, (a0.w - st.x) * st.y * s0.w + b0.w);
  pk.z = pkbf((a1.x - st.x) * st.y * s1.x + b1.x, (a1.y - st.x) * st.y * s1.y + b1.y);
  pk.w = pkbf((a1.z - st.x) * st.y * s1.z + b1.z, (a1.w - st.x) * st.y * s1.w + b1.w);
  *(uint4*)(h + (size_t)i * 8) = pk;
}

// ---------------- weight transpose + cast: [512][512] f32 -> [512][512]^T bf16 ----------------
__global__ __launch_bounds__(256) void wtrans_kernel(const float* __restrict__ w0,
                                                     const float* __restrict__ w1,
                                                     const float* __restrict__ w2,
                                                     const float* __restrict__ w3,
                                                     ushort* __restrict__ wT) {
  __shared__ float tile[64][65];
  int mat = blockIdx.y;
  const float* w = (mat == 0) ? w0 : (mat == 1) ? w1 : (mat == 2) ? w2 : w3;
  int tr = (blockIdx.x >> 3) * 64;  // source row block
  int tc = (blockIdx.x & 7) * 64;   // source col block
  int ty = threadIdx.x >> 6, tx = threadIdx.x & 63;
  #pragma unroll
  for (int i = 0; i < 16; i++) {
    int r = i * 4 + ty;
    tile[r][tx] = w[(size_t)(tr + r) * 512 + tc + tx];
  }
  __syncthreads();
  #pragma unroll
  for (int i = 0; i < 16; i++) {
    int r = i * 4 + ty;  // output row = tc + r
    wT[((size_t)mat << 18) + (size_t)(tc + r) * 512 + tr + tx] = f2bf(tile[tx][r]);
  }
}

// ---------------- fused QKV GEMM: [8192x512] x [512x1536] ----------------
__global__ __launch_bounds__(256) void qkv_gemm_kernel(const ushort* __restrict__ h,
                                                       const ushort* __restrict__ wT,
                                                       const float* __restrict__ bq,
                                                       const float* __restrict__ bk,
                                                       const float* __restrict__ bv,
                                                       ushort* __restrict__ qo,
                                                       ushort* __restrict__ ko,
                                                       ushort* __restrict__ vT) {
  const int l = threadIdx.x & 63;
  const int w = threadIdx.x >> 6;
  const int lr = l & 15, lg = l >> 4;
  const int m0 = blockIdx.x * 128 + (w >> 1) * 64;
  const int n0 = blockIdx.y * 128 + (w & 1) * 64;

  const ushort* ap = h  + (size_t)(m0 + lr) * C + lg * 8;
  const ushort* bp = wT + (size_t)(n0 + lr) * C + lg * 8;

  f32x4 acc[4][4] = {};
  for (int k = 0; k < C; k += 32) {
    bf16x8 af[4], bfr[4];
    #pragma unroll
    for (int i = 0; i < 4; i++) af[i]  = *(const bf16x8*)(ap + (size_t)i * 16 * C + k);
    #pragma unroll
    for (int i = 0; i < 4; i++) bfr[i] = *(const bf16x8*)(bp + (size_t)i * 16 * C + k);
    #pragma unroll
    for (int mi = 0; mi < 4; mi++)
      #pragma unroll
      for (int ni = 0; ni < 4; ni++)
        acc[mi][ni] = MFMA16(af[mi], bfr[ni], acc[mi][ni]);
  }

  const int mat = n0 >> 9;  // uniform per block
  #pragma unroll
  for (int mi = 0; mi < 4; mi++) {
    #pragma unroll
    for (int ni = 0; ni < 4; ni++) {
      #pragma unroll
      for (int r = 0; r < 4; r++) {
        int srow = m0 + mi * 16 + lg * 4 + r;
        int nl = (n0 + ni * 16 + lr) & 511;
        float v = acc[mi][ni][r];
        if (mat == 0) {
          qo[(size_t)srow * C + nl] = f2bf((v + bq[nl]) * QSCALE);
        } else if (mat == 1) {
          ko[(size_t)srow * C + nl] = f2bf(v + bk[nl]);
        } else {
          vT[((size_t)(srow >> 12) * C + nl) * S + (srow & (S - 1))] = f2bf(v + bv[nl]);
        }
      }
    }
  }
}

// ---------------- flash attention, split-K 2-way, 4-deep pipelined K/V staging ----------------
// grid (32, 16, 2). Block: 4 waves x 32 q-rows. KVBLK=32, 4 LDS buffers each for K and V,
// prefetch distance 3, counted vmcnt (never 0) + raw s_barrier (T3/T4). Unroll 4 so buffer
// indices and LDS addresses are compile-time constants.
__global__ __launch_bounds__(256, 4) void attn_kernel(const ushort* __restrict__ q,
                                                      const ushort* __restrict__ k,
                                                      const ushort* __restrict__ vT,
                                                      ushort* __restrict__ po0,
                                                      ushort* __restrict__ po1,
                                                      float* __restrict__ pm,
                                                      float* __restrict__ pl) {
  __shared__ ushort Kt[4][32 * 64];   // [buf][key][d]   16 KB
  __shared__ ushort Vt[4][64 * 32];   // [buf][d][key]   16 KB
  __shared__ ushort Plds[4][32 * 32]; // per-wave P       8 KB

  const int l = threadIdx.x & 63;
  const int wid = threadIdx.x >> 6;
  const int lr = l & 15, lg = l >> 4;
  const int bh = blockIdx.y;           // 0..15
  const int b = bh >> 3, hh = bh & 7;
  const int q0 = blockIdx.x * 128 + wid * 32;
  const int half = blockIdx.z;
  const int k0 = half * (S / 2);
  constexpr int KB = 32;
  constexpr int NT = (S / 2) / KB;     // 64 tiles

  const ushort* qp = q + ((size_t)(b * S + q0)) * C + hh * HD;
  const ushort* kp = k + ((size_t)(b * S + k0)) * C + hh * HD;
  const ushort* vp = vT + ((size_t)(b * C) + hh * HD) * S + k0;

  // K staging: lane l stages row (wid*8 + l>>3), 16B chunk (l&7), XOR-swizzled source
  const int krow = wid * 8 + (l >> 3);
  const int ksc  = (l & 7) ^ (krow & 7);
  // V staging: lane l stages d-row (wid*16 + l>>2), 16B chunk (l&3), linear
  const int vrow = wid * 16 + (l >> 2);
  const int vsc  = l & 3;

  // Q fragments: B-frag for swapped QK^T = Q[q=mi*16+lr][d=kk*32+lg*8..+7]
  bf16x8 qa[2][2];
  #pragma unroll
  for (int mi = 0; mi < 2; mi++)
    #pragma unroll
    for (int kk = 0; kk < 2; kk++)
      qa[mi][kk] = *(const bf16x8*)(qp + (size_t)(mi * 16 + lr) * C + kk * 32 + lg * 8);

  f32x4 oacc[2][4] = {};
  float mst[2], lst[2];   // per-lane stats for q = mi*16+lr (partial over lg)
  mst[0] = mst[1] = -1e30f;
  lst[0] = lst[1] = 0.f;

  // prologue: stage tiles 0,1,2
  #pragma unroll
  for (int t = 0; t < 3; t++) {
    GLOAD_LDS16(kp + (size_t)(t * KB + krow) * C + ksc * 8, &Kt[t][wid * 8 * 64]);
    GLOAD_LDS16(vp + (size_t)vrow * S + t * KB + vsc * 8, &Vt[t][wid * 16 * 32]);
  }
  asm volatile("s_waitcnt vmcnt(4)" ::: "memory");
  __builtin_amdgcn_sched_barrier(0);
  __builtin_amdgcn_s_barrier();
  __builtin_amdgcn_sched_barrier(0);

  for (int base = 0; base < NT; base += 4) {
    #pragma unroll
    for (int u = 0; u < 4; u++) {
      const int t = base + u;
      const int buf = u;                 // t & 3 == u (base % 4 == 0)
      const int nbuf = (u + 3) & 3;
      // issue prefetch of tile t+3
      if (t + 3 < NT) {
        GLOAD_LDS16(kp + (size_t)((t + 3) * KB + krow) * C + ksc * 8, &Kt[nbuf][wid * 8 * 64]);
        GLOAD_LDS16(vp + (size_t)vrow * S + (t + 3) * KB + vsc * 8, &Vt[nbuf][wid * 16 * 32]);
      }

      // S^T tile = mfma(K, Q): sacc[mi][ni][r] = S[q=mi*16+lr][key=ni*16+lg*4+r]
      __builtin_amdgcn_s_setprio(1);
      f32x4 sacc[2][2] = {};
      #pragma unroll
      for (int kk = 0; kk < 2; kk++) {
        #pragma unroll
        for (int ni = 0; ni < 2; ni++) {
          bf16x8 kf = *(const bf16x8*)&Kt[buf][(ni * 16 + lr) * 64 + (((kk * 4 + lg) ^ (lr & 7)) * 8)];
          #pragma unroll
          for (int mi = 0; mi < 2; mi++)
            sacc[mi][ni] = MFMA16(kf, qa[mi][kk], sacc[mi][ni]);
        }
      }
      __builtin_amdgcn_s_setprio(0);

      // per-lane max over this lane's 8 keys; defer-max check
      float lm[2];
      int grow = 0;
      #pragma unroll
      for (int mi = 0; mi < 2; mi++) {
        float mx = sacc[mi][0][0];
        #pragma unroll
        for (int ni = 0; ni < 2; ni++)
          #pragma unroll
          for (int r = 0; r < 4; r++) mx = fmaxf(mx, sacc[mi][ni][r]);
        lm[mi] = mx;
        grow |= (mx > mst[mi] + DEFER_THR) ? 1 : 0;
      }
      if (__any(grow)) {
        #pragma unroll
        for (int mi = 0; mi < 2; mi++) {
          float mx = lm[mi];
          mx = fmaxf(mx, __shfl_xor(mx, 16));
          mx = fmaxf(mx, __shfl_xor(mx, 32));
          float mnew = fmaxf(mst[mi], mx);
          float a = __builtin_amdgcn_exp2f(mst[mi] - mnew);
          mst[mi] = mnew;
          lst[mi] *= a;
          // oacc rows are q = mi*16 + lg*4 + r; their 'a' lives in lane (lg*4+r)
          #pragma unroll
          for (int r = 0; r < 4; r++) {
            float ar = __shfl(a, lg * 4 + r);
            #pragma unroll
            for (int nd = 0; nd < 4; nd++) oacc[mi][nd][r] *= ar;
          }
        }
      }

      // P = exp2(S - m): cvt_pk pack -> Plds (16B-granule XOR swizzle)
      #pragma unroll
      for (int mi = 0; mi < 2; mi++) {
        float m = mst[mi];
        int row = mi * 16 + lr;
        float ps = 0.f;
        #pragma unroll
        for (int ni = 0; ni < 2; ni++) {
          float p0 = __builtin_amdgcn_exp2f(sacc[mi][ni][0] - m);
          float p1 = __builtin_amdgcn_exp2f(sacc[mi][ni][1] - m);
          float p2 = __builtin_amdgcn_exp2f(sacc[mi][ni][2] - m);
          float p3 = __builtin_amdgcn_exp2f(sacc[mi][ni][3] - m);
          ps += (p0 + p1) + (p2 + p3);
          int chunk = (ni * 2 + (lg >> 1)) ^ (lr & 3);
          *(uint2*)((char*)&Plds[wid][row * 32] + chunk * 16 + (lg & 1) * 8) =
              make_uint2(cvtpk(p0, p1), cvtpk(p2, p3));
        }
        lst[mi] += ps;
      }

      // O += P * V
      __builtin_amdgcn_s_setprio(1);
      bf16x8 pa[2];
      #pragma unroll
      for (int mi = 0; mi < 2; mi++) {
        int row = mi * 16 + lr;
        pa[mi] = *(const bf16x8*)((const char*)&Plds[wid][row * 32] + (lg ^ (lr & 3)) * 16);
      }
      #pragma unroll
      for (int nd = 0; nd < 4; nd++) {
        bf16x8 vf = *(const bf16x8*)&Vt[buf][(nd * 16 + lr) * 32 + lg * 8];
        #pragma unroll
        for (int mi = 0; mi < 2; mi++)
          oacc[mi][nd] = MFMA16(pa[mi], vf, oacc[mi][nd]);
      }
      __builtin_amdgcn_s_setprio(0);

      // counted vmcnt: t+1's loads must have landed; t+2/t+3 (4 loads) stay in flight
      asm volatile("s_waitcnt vmcnt(4)" ::: "memory");
      __builtin_amdgcn_sched_barrier(0);
      __builtin_amdgcn_s_barrier();
      __builtin_amdgcn_sched_barrier(0);
    }
  }

  // epilogue: reduce per-lane l partials over lg, store partial O + m + l
  ushort* po = half ? po1 : po0;
  #pragma unroll
  for (int mi = 0; mi < 2; mi++) {
    float lsum = lst[mi];
    lsum += __shfl_xor(lsum, 16);
    lsum += __shfl_xor(lsum, 32);
    if (lg == 0) {
      int rid_s = bh * S + q0 + mi * 16 + lr;
      pm[half * NROWS + rid_s] = mst[mi];
      pl[half * NROWS + rid_s] = lsum;
    }
    #pragma unroll
    for (int r = 0; r < 4; r++) {
      int rid = bh * S + q0 + mi * 16 + lg * 4 + r;
      #pragma unroll
      for (int nd = 0; nd < 4; nd++)
        po[(size_t)rid * HD + nd * 16 + lr] = f2bf(oacc[mi][nd][r]);
    }
  }
}

// ---------------- split-K combine: normalize and merge halves ----------------
__global__ __launch_bounds__(256) void attn_combine_kernel(const ushort* __restrict__ po0,
                                                           const ushort* __restrict__ po1,
                                                           const float* __restrict__ pm,
                                                           const float* __restrict__ pl,
                                                           ushort* __restrict__ o) {
  int rid = blockIdx.x * 4 + (threadIdx.x >> 6);
  int d = threadIdx.x & 63;
  float m1 = pm[rid], m2 = pm[NROWS + rid];
  float l1 = pl[rid], l2 = pl[NROWS + rid];
  float m = fmaxf(m1, m2);
  float w1 = __builtin_amdgcn_exp2f(m1 - m);
  float w2 = __builtin_amdgcn_exp2f(m2 - m);
  float denom = w1 * l1 + w2 * l2;
  float o1 = (float)__builtin_bit_cast(__hip_bfloat16, (unsigned short)po0[(size_t)rid * HD + d]);
  float o2 = (float)__builtin_bit_cast(__hip_bfloat16, (unsigned short)po1[(size_t)rid * HD + d]);
  float val = (w1 * o1 + w2 * o2) / denom;
  int b = rid >> 15, hh = (rid >> 12) & 7, qq = rid & (S - 1);
  o[((size_t)(b * S + qq)) * C + hh * HD + d] = f2bf(val);
}

// ---------------- O-projection + bias + residual ----------------
__global__ __launch_bounds__(256) void oproj_gemm_kernel(const ushort* __restrict__ o,
                                                         const ushort* __restrict__ woT,
                                                         const float* __restrict__ x,
                                                         const float* __restrict__ bo,
                                                         float* __restrict__ out) {
  const int l = threadIdx.x & 63;
  const int w = threadIdx.x >> 6;
  const int lr = l & 15, lg = l >> 4;
  const int m0 = blockIdx.x * 128 + (w >> 1) * 64;
  const int n0 = blockIdx.y * 128 + (w & 1) * 64;

  const ushort* ap = o   + (size_t)(m0 + lr) * C + lg * 8;
  const ushort* bp = woT + (size_t)(n0 + lr) * C + lg * 8;

  f32x4 acc[4][4] = {};
  for (int k = 0; k < C; k += 32) {
    bf16x8 af[4], bfr[4];
    #pragma unroll
    for (int i = 0; i < 4; i++) af[i]  = *(const bf16x8*)(ap + (size_t)i * 16 * C + k);
    #pragma unroll
    for (int i = 0; i < 4; i++) bfr[i] = *(const bf16x8*)(bp + (size_t)i * 16 * C + k);
    #pragma unroll
    for (int mi = 0; mi < 4; mi++)
      #pragma unroll
      for (int ni = 0; ni < 4; ni++)
        acc[mi][ni] = MFMA16(af[mi], bfr[ni], acc[mi][ni]);
  }

  #pragma unroll
  for (int mi = 0; mi < 4; mi++) {
    #pragma unroll
    for (int ni = 0; ni < 4; ni++) {
      #pragma unroll
      for (int r = 0; r < 4; r++) {
        int srow = m0 + mi * 16 + lg * 4 + r;
        int c = n0 + ni * 16 + lr;
        out[(size_t)srow * C + c] = x[(size_t)srow * C + c] + acc[mi][ni][r] + bo[c];
      }
    }
  }
}

extern "C" void kernel_launch(void* const* d_in, const int* in_sizes, int n_in,
                              void* d_out, int out_size, void* d_ws, size_t ws_size,
                              hipStream_t stream) {
  const float* x  = (const float*)d_in[0];
  const float* gs = (const float*)d_in[1];
  const float* gb = (const float*)d_in[2];
  const float* wq = (const float*)d_in[3];
  const float* bq = (const float*)d_in[4];
  const float* wk = (const float*)d_in[5];
  const float* bk = (const float*)d_in[6];
  const float* wv = (const float*)d_in[7];
  const float* bv = (const float*)d_in[8];
  const float* wo = (const float*)d_in[9];
  const float* bo = (const float*)d_in[10];

  char* ws = (char*)d_ws;
  ushort* h    = (ushort*)(ws);                    // 8 MB  [M][C] bf16 (dead after qkv -> reused as po1)
  ushort* wT   = (ushort*)(ws + 8388608);          // 2 MB  [2048][512] bf16 (wqT,wkT,wvT,woT)
  ushort* qb   = (ushort*)(ws + 10485760);         // 8 MB  [M][512] bf16 (dead after attn -> reused as final O)
  ushort* kb   = (ushort*)(ws + 18874368);         // 8 MB  [M][512] bf16
  ushort* vTb  = (ushort*)(ws + 27262976);         // 8 MB  [B][512][S] bf16 (transposed)
  ushort* po0  = (ushort*)(ws + 35651584);         // 8 MB  [NROWS][64] bf16 partial O half 0
  float2* st   = (float2*)(ws + 44040192);         // 512 B
  float*  pm   = (float*)(ws + 44041216);          // 512 KB [2][NROWS]
  float*  pl   = (float*)(ws + 44565504);          // 512 KB [2][NROWS]
  ushort* po1  = h;                                // overlay: h is dead after qkv_gemm
  ushort* ofin = qb;                               // overlay: q is dead after attn

  gn_stats_kernel<<<64, 256, 0, stream>>>(x, st);
  wtrans_kernel<<<dim3(64, 4), 256, 0, stream>>>(wq, wk, wv, wo, wT);
  gn_apply_kernel<<<2048, 256, 0, stream>>>(x, gs, gb, st, h);
  qkv_gemm_kernel<<<dim3(64, 12), 256, 0, stream>>>(h, wT, bq, bk, bv, qb, kb, vTb);
  attn_kernel<<<dim3(32, 16, 2), 256, 0, stream>>>(qb, kb, vTb, po0, po1, pm, pl);
  attn_combine_kernel<<<16384, 256, 0, stream>>>(po0, po1, pm, pl, ofin);
  oproj_gemm_kernel<<<dim3(64, 4), 256, 0, stream>>>(ofin, wT + 786432, x, bo, (float*)d_out);
}

// Round 7
// 185.280 us; speedup vs baseline: 1.1436x; 1.1436x over previous
//
#include <hip/hip_runtime.h>
#include <hip/hip_bf16.h>

typedef __attribute__((ext_vector_type(8))) short bf16x8;
typedef __attribute__((ext_vector_type(4))) float f32x4;
typedef __attribute__((ext_vector_type(16))) float f32x16;

#define MFMA16(a, b, c) __builtin_amdgcn_mfma_f32_16x16x32_bf16(a, b, c, 0, 0, 0)
#define MFMA32(a, b, c) __builtin_amdgcn_mfma_f32_32x32x16_bf16(a, b, c, 0, 0, 0)

static constexpr int Bn = 2;
static constexpr int S  = 4096;   // H*W
static constexpr int C  = 512;
static constexpr int NH = 8;
static constexpr int HD = 64;
static constexpr int M  = Bn * S; // 8192
static constexpr int NROWS = Bn * NH * S;  // 65536 (b,h,q) rows

// q pre-scale: hd^-1/2 * log2(e)  (softmax computed in base-2 domain)
#define QSCALE 0.18033688f
#define DEFER_THR 8.0f

__device__ __forceinline__ ushort f2bf(float f) {
  unsigned u = __builtin_bit_cast(unsigned, f);
  u += 0x7fffu + ((u >> 16) & 1u);
  return (ushort)(u >> 16);
}

__device__ __forceinline__ unsigned pkbf(float a, float b) {
  return (unsigned)f2bf(a) | ((unsigned)f2bf(b) << 16);
}

// hardware packed f32->bf16 (RNE), lo=a hi=b
__device__ __forceinline__ unsigned cvtpk(float a, float b) {
  unsigned r;
  asm("v_cvt_pk_bf16_f32 %0, %1, %2" : "=v"(r) : "v"(a), "v"(b));
  return r;
}

#define GLOAD_LDS16(g, l) __builtin_amdgcn_global_load_lds( \
    (const __attribute__((address_space(1))) unsigned*)(const void*)(g), \
    (__attribute__((address_space(3))) unsigned*)(void*)(l), 16, 0, 0)

// ---------------- GroupNorm stats: one block per (b, group) ----------------
__global__ __launch_bounds__(256) void gn_stats_kernel(const float* __restrict__ x,
                                                       float2* __restrict__ stats) {
  int bg = blockIdx.x;            // 0..63
  int b = bg >> 5, g = bg & 31;
  const float* xp = x + (size_t)b * S * C + g * 16;
  float sum = 0.f, sq = 0.f;
  for (int s = threadIdx.x; s < S; s += 256) {
    const float4* p = (const float4*)(xp + (size_t)s * C);
    #pragma unroll
    for (int i = 0; i < 4; i++) {
      float4 v = p[i];
      sum += v.x + v.y + v.z + v.w;
      sq  += v.x * v.x + v.y * v.y + v.z * v.z + v.w * v.w;
    }
  }
  #pragma unroll
  for (int d = 1; d < 64; d <<= 1) {
    sum += __shfl_xor(sum, d);
    sq  += __shfl_xor(sq, d);
  }
  __shared__ float2 red[4];
  if ((threadIdx.x & 63) == 0) red[threadIdx.x >> 6] = make_float2(sum, sq);
  __syncthreads();
  if (threadIdx.x == 0) {
    float s0 = 0.f, q0 = 0.f;
    #pragma unroll
    for (int i = 0; i < 4; i++) { s0 += red[i].x; q0 += red[i].y; }
    float inv = 1.f / (float)(S * 16);
    float mean = s0 * inv;
    float var = q0 * inv - mean * mean;
    stats[bg] = make_float2(mean, rsqrtf(var + 1e-6f));
  }
}

// ---------------- GroupNorm apply + cast to bf16 ----------------
__global__ __launch_bounds__(256) void gn_apply_kernel(const float* __restrict__ x,
                                                       const float* __restrict__ sc,
                                                       const float* __restrict__ bi,
                                                       const float2* __restrict__ stats,
                                                       ushort* __restrict__ h) {
  int i = blockIdx.x * 256 + threadIdx.x;   // 0..524287, 8 channels each
  int s = i >> 6;
  int c0 = (i & 63) << 3;
  int b = s >> 12;
  float2 st = stats[(b << 5) + (c0 >> 4)];
  const float4* xv = (const float4*)(x + (size_t)s * C + c0);
  const float4* sv = (const float4*)(sc + c0);
  const float4* bv = (const float4*)(bi + c0);
  float4 a0 = xv[0], a1 = xv[1];
  float4 s0 = sv[0], s1 = sv[1];
  float4 b0 = bv[0], b1 = bv[1];
  uint4 pk;
  pk.x = pkbf((a0.x - st.x) * st.y * s0.x + b0.x, (a0.y - st.x) * st.y * s0.y + b0.y);
  pk.y = pkbf((a0.z - st.x) * st.y * s0.z + b0.z, (a0.w - st.x) * st.y * s0.w + b0.w);
  pk.z = pkbf((a1.x - st.x) * st.y * s1.x + b1.x, (a1.y - st.x) * st.y * s1.y + b1.y);
  pk.w = pkbf((a1.z - st.x) * st.y * s1.z + b1.z, (a1.w - st.x) * st.y * s1.w + b1.w);
  *(uint4*)(h + (size_t)i * 8) = pk;
}

// ---------------- weight transpose + cast: [512][512] f32 -> [512][512]^T bf16 ----------------
__global__ __launch_bounds__(256) void wtrans_kernel(const float* __restrict__ w0,
                                                     const float* __restrict__ w1,
                                                     const float* __restrict__ w2,
                                                     const float* __restrict__ w3,
                                                     ushort* __restrict__ wT) {
  __shared__ float tile[64][65];
  int mat = blockIdx.y;
  const float* w = (mat == 0) ? w0 : (mat == 1) ? w1 : (mat == 2) ? w2 : w3;
  int tr = (blockIdx.x >> 3) * 64;  // source row block
  int tc = (blockIdx.x & 7) * 64;   // source col block
  int ty = threadIdx.x >> 6, tx = threadIdx.x & 63;
  #pragma unroll
  for (int i = 0; i < 16; i++) {
    int r = i * 4 + ty;
    tile[r][tx] = w[(size_t)(tr + r) * 512 + tc + tx];
  }
  __syncthreads();
  #pragma unroll
  for (int i = 0; i < 16; i++) {
    int r = i * 4 + ty;  // output row = tc + r
    wT[((size_t)mat << 18) + (size_t)(tc + r) * 512 + tr + tx] = f2bf(tile[tx][r]);
  }
}

// ---------------- fused QKV GEMM, m97-style LDS staging: [8192x512] x [512x1536] ----------------
__global__ __launch_bounds__(256, 3) void qkv_gemm_kernel(const ushort* __restrict__ h,
                                                          const ushort* __restrict__ wT,
                                                          const float* __restrict__ bq,
                                                          const float* __restrict__ bk,
                                                          const float* __restrict__ bv,
                                                          ushort* __restrict__ qo,
                                                          ushort* __restrict__ ko,
                                                          ushort* __restrict__ vT) {
  __shared__ ushort As[2][128 * 32];
  __shared__ ushort Bs[2][128 * 32];
  const int t = threadIdx.x;
  const int l = t & 63;
  const int w = t >> 6;
  const int lr = l & 15, lg = l >> 4;
  const int m0 = blockIdx.x * 128, n0 = blockIdx.y * 128;
  const int mw = (w >> 1) * 64, nw = (w & 1) * 64;

  const ushort* Ab = h  + (size_t)m0 * C;
  const ushort* Bb = wT + (size_t)n0 * C;

  // prologue: stage k-step 0
  {
    GLOAD_LDS16(Ab + (size_t)(t >> 2) * C + (t & 3) * 8,           &As[0][t * 8]);
    GLOAD_LDS16(Ab + (size_t)(64 + (t >> 2)) * C + (t & 3) * 8,    &As[0][(t + 256) * 8]);
    GLOAD_LDS16(Bb + (size_t)(t >> 2) * C + (t & 3) * 8,           &Bs[0][t * 8]);
    GLOAD_LDS16(Bb + (size_t)(64 + (t >> 2)) * C + (t & 3) * 8,    &Bs[0][(t + 256) * 8]);
  }
  __syncthreads();

  f32x4 acc[4][4] = {};
  int buf = 0;
  for (int kt = 0; kt < 16; kt++) {
    if (kt + 1 < 16) {
      int k0 = (kt + 1) * 32;
      GLOAD_LDS16(Ab + (size_t)(t >> 2) * C + k0 + (t & 3) * 8,        &As[buf ^ 1][t * 8]);
      GLOAD_LDS16(Ab + (size_t)(64 + (t >> 2)) * C + k0 + (t & 3) * 8, &As[buf ^ 1][(t + 256) * 8]);
      GLOAD_LDS16(Bb + (size_t)(t >> 2) * C + k0 + (t & 3) * 8,        &Bs[buf ^ 1][t * 8]);
      GLOAD_LDS16(Bb + (size_t)(64 + (t >> 2)) * C + k0 + (t & 3) * 8, &Bs[buf ^ 1][(t + 256) * 8]);
    }
    bf16x8 af[4], bfr[4];
    #pragma unroll
    for (int i = 0; i < 4; i++) af[i]  = *(const bf16x8*)&As[buf][(mw + i * 16 + lr) * 32 + lg * 8];
    #pragma unroll
    for (int i = 0; i < 4; i++) bfr[i] = *(const bf16x8*)&Bs[buf][(nw + i * 16 + lr) * 32 + lg * 8];
    #pragma unroll
    for (int mi = 0; mi < 4; mi++)
      #pragma unroll
      for (int ni = 0; ni < 4; ni++)
        acc[mi][ni] = MFMA16(af[mi], bfr[ni], acc[mi][ni]);
    __syncthreads();
    buf ^= 1;
  }

  const int mat = n0 >> 9;  // uniform per block
  #pragma unroll
  for (int mi = 0; mi < 4; mi++) {
    #pragma unroll
    for (int ni = 0; ni < 4; ni++) {
      #pragma unroll
      for (int r = 0; r < 4; r++) {
        int srow = m0 + mw + mi * 16 + lg * 4 + r;
        int nl = (n0 + nw + ni * 16 + lr) & 511;
        float v = acc[mi][ni][r];
        if (mat == 0) {
          qo[(size_t)srow * C + nl] = f2bf((v + bq[nl]) * QSCALE);
        } else if (mat == 1) {
          ko[(size_t)srow * C + nl] = f2bf(v + bk[nl]);
        } else {
          vT[((size_t)(srow >> 12) * C + nl) * S + (srow & (S - 1))] = f2bf(v + bv[nl]);
        }
      }
    }
  }
}

// ---------------- flash attention, split-K 2-way, 32x32 MFMA, in-register P (T12) ----------------
// grid (32, 16, 2). Block: 4 waves x 32 q-rows. KVBLK=64, double-buffered K/V LDS
// ([64][64] bf16, 128B rows, 8-chunk XOR swizzle -> conflict-free). Swapped QK^T with
// mfma_32x32x16: lane holds S[q=l&31][16 of 32 keys]; P->bf16 via v_cvt_pk; PV A-frags
// built with lane<->lane+32 half-exchange (shfl_xor 32) — NO LDS for P.
__global__ __launch_bounds__(256, 4) void attn_kernel(const ushort* __restrict__ q,
                                                      const ushort* __restrict__ k,
                                                      const ushort* __restrict__ vT,
                                                      ushort* __restrict__ po0,
                                                      ushort* __restrict__ po1,
                                                      float* __restrict__ pm,
                                                      float* __restrict__ pl) {
  __shared__ ushort Kt[2][64 * 64];   // [buf][key][d]
  __shared__ ushort Vt[2][64 * 64];   // [buf][d][key]

  const int l = threadIdx.x & 63;
  const int wid = threadIdx.x >> 6;
  const int l31 = l & 31;
  const int hi = l >> 5;
  const int bh = blockIdx.y;           // 0..15
  const int b = bh >> 3, hh = bh & 7;
  const int q0 = blockIdx.x * 128 + wid * 32;
  const int half = blockIdx.z;
  const int k0 = half * (S / 2);
  constexpr int NT = (S / 2) / 64;     // 32 tiles

  const ushort* qp = q + ((size_t)(b * S + q0)) * C + hh * HD;
  const ushort* kp = k + ((size_t)(b * S + k0)) * C + hh * HD;
  const ushort* vp = vT + ((size_t)(b * C) + hh * HD) * S + k0;

  // staging geometry (same as R5): this thread stages rows srow, srow+8; chunk sc
  const int srow = wid * 16 + (l >> 3);
  const int sc   = l & 7;

  // Q B-frags: Q[q = q0 + l31][k = kd*16 + hi*8 .. +7]
  bf16x8 qa[4];
  #pragma unroll
  for (int kd = 0; kd < 4; kd++)
    qa[kd] = *(const bf16x8*)(qp + (size_t)l31 * C + kd * 16 + hi * 8);

  f32x16 oacc[2] = {};       // [nd]: O[q=crow(r,hi)][d=nd*32+l31]
  float mst = -1e30f;        // running max for q = q0 + l31 (synced across hi pair)
  float lst = 0.f;           // per-lane partial sum (own 16-key subsets)

  // prologue: stage tile 0 into buf 0
  #pragma unroll
  for (int j = 0; j < 2; j++) {
    int r = srow + j * 8;
    GLOAD_LDS16(kp + (size_t)r * C + ((sc ^ (r & 7)) * 8), &Kt[0][(wid * 2 + j) * 512]);
    GLOAD_LDS16(vp + (size_t)r * S + ((sc ^ (r & 7)) * 8), &Vt[0][(wid * 2 + j) * 512]);
  }
  __syncthreads();

  int buf = 0;
  for (int kt = 0; kt < NT; kt++) {
    // issue next tile's staging (lands during this tile's compute)
    if (kt + 1 < NT) {
      #pragma unroll
      for (int j = 0; j < 2; j++) {
        int r = srow + j * 8;
        GLOAD_LDS16(kp + (size_t)((kt + 1) * 64 + r) * C + ((sc ^ (r & 7)) * 8),
                    &Kt[buf ^ 1][(wid * 2 + j) * 512]);
        GLOAD_LDS16(vp + (size_t)r * S + (kt + 1) * 64 + ((sc ^ (r & 7)) * 8),
                    &Vt[buf ^ 1][(wid * 2 + j) * 512]);
      }
    }

    #pragma unroll
    for (int kn = 0; kn < 2; kn++) {
      // S^T = mfma32(K, Q): s[r] = S[q = l31][key = kn*32 + crow(r,hi)]
      f32x16 s = {};
      #pragma unroll
      for (int kd = 0; kd < 4; kd++) {
        int krow = kn * 32 + l31;
        bf16x8 kf = *(const bf16x8*)&Kt[buf][krow * 64 + (((kd * 2 + hi) ^ (krow & 7)) * 8)];
        s = MFMA32(kf, qa[kd], s);
      }

      // per-lane max over own 16 keys
      float lmax = s[0];
      #pragma unroll
      for (int r = 1; r < 16; r++) lmax = fmaxf(lmax, s[r]);

      if (__any(lmax > mst + DEFER_THR)) {
        float m2 = fmaxf(lmax, __shfl_xor(lmax, 32));
        float mnew = fmaxf(mst, m2);
        float a = __builtin_amdgcn_exp2f(mst - mnew);
        mst = mnew;
        lst *= a;
        #pragma unroll
        for (int r = 0; r < 16; r++) {
          float ar = __shfl(a, (r & 3) + 8 * (r >> 2) + 4 * hi);
          oacc[0][r] *= ar;
          oacc[1][r] *= ar;
        }
      }

      // P = exp2(s - m), per-lane partial sum, pack to bf16
      float e[16];
      float ps = 0.f;
      #pragma unroll
      for (int r = 0; r < 16; r++) {
        e[r] = __builtin_amdgcn_exp2f(s[r] - mst);
        ps += e[r];
      }
      lst += ps;
      unsigned pw[8];
      #pragma unroll
      for (int j = 0; j < 8; j++) pw[j] = cvtpk(e[2 * j], e[2 * j + 1]);

      // PV: A-frags via half-exchange; two K=16 chunks per kn
      #pragma unroll
      for (int kc = 0; kc < 2; kc++) {
        unsigned wa0 = pw[kc * 4 + 0], wa1 = pw[kc * 4 + 1];
        unsigned wb0 = pw[kc * 4 + 2], wb1 = pw[kc * 4 + 3];
        unsigned xb0 = __shfl_xor(wb0, 32), xb1 = __shfl_xor(wb1, 32);
        unsigned xa0 = __shfl_xor(wa0, 32), xa1 = __shfl_xor(wa1, 32);
        union { unsigned u[4]; bf16x8 v; } pu;
        pu.u[0] = hi ? xb0 : wa0;
        pu.u[1] = hi ? xb1 : wa1;
        pu.u[2] = hi ? wb0 : xa0;
        pu.u[3] = hi ? wb1 : xa1;
        #pragma unroll
        for (int nd = 0; nd < 2; nd++) {
          int vrow = nd * 32 + l31;
          bf16x8 vf = *(const bf16x8*)&Vt[buf][vrow * 64 + (((kn * 4 + kc * 2 + hi) ^ (vrow & 7)) * 8)];
          oacc[nd] = MFMA32(pu.v, vf, oacc[nd]);
        }
      }
    }

    __syncthreads();
    buf ^= 1;
  }

  // epilogue: merge partner partial sums, store unnormalized O + stats
  ushort* po = half ? po1 : po0;
  float lfull = lst + __shfl_xor(lst, 32);
  if (hi == 0) {
    int rid_s = bh * S + q0 + l31;
    pm[half * NROWS + rid_s] = mst;
    pl[half * NROWS + rid_s] = lfull;
  }
  #pragma unroll
  for (int r = 0; r < 16; r++) {
    int rid = bh * S + q0 + (r & 3) + 8 * (r >> 2) + 4 * hi;
    po[(size_t)rid * HD + l31]      = f2bf(oacc[0][r]);
    po[(size_t)rid * HD + 32 + l31] = f2bf(oacc[1][r]);
  }
}

// ---------------- split-K combine: normalize and merge halves ----------------
__global__ __launch_bounds__(256) void attn_combine_kernel(const ushort* __restrict__ po0,
                                                           const ushort* __restrict__ po1,
                                                           const float* __restrict__ pm,
                                                           const float* __restrict__ pl,
                                                           ushort* __restrict__ o) {
  int rid = blockIdx.x * 4 + (threadIdx.x >> 6);
  int d = threadIdx.x & 63;
  float m1 = pm[rid], m2 = pm[NROWS + rid];
  float l1 = pl[rid], l2 = pl[NROWS + rid];
  float m = fmaxf(m1, m2);
  float w1 = __builtin_amdgcn_exp2f(m1 - m);
  float w2 = __builtin_amdgcn_exp2f(m2 - m);
  float denom = w1 * l1 + w2 * l2;
  float o1 = (float)__builtin_bit_cast(__hip_bfloat16, (unsigned short)po0[(size_t)rid * HD + d]);
  float o2 = (float)__builtin_bit_cast(__hip_bfloat16, (unsigned short)po1[(size_t)rid * HD + d]);
  float val = (w1 * o1 + w2 * o2) / denom;
  int b = rid >> 15, hh = (rid >> 12) & 7, qq = rid & (S - 1);
  o[((size_t)(b * S + qq)) * C + hh * HD + d] = f2bf(val);
}

// ---------------- O-projection + bias + residual, m97-style staging ----------------
__global__ __launch_bounds__(256, 3) void oproj_gemm_kernel(const ushort* __restrict__ o,
                                                            const ushort* __restrict__ woT,
                                                            const float* __restrict__ x,
                                                            const float* __restrict__ bo,
                                                            float* __restrict__ out) {
  __shared__ ushort As[2][128 * 32];
  __shared__ ushort Bs[2][128 * 32];
  const int t = threadIdx.x;
  const int l = t & 63;
  const int w = t >> 6;
  const int lr = l & 15, lg = l >> 4;
  const int m0 = blockIdx.x * 128, n0 = blockIdx.y * 128;
  const int mw = (w >> 1) * 64, nw = (w & 1) * 64;

  const ushort* Ab = o   + (size_t)m0 * C;
  const ushort* Bb = woT + (size_t)n0 * C;

  {
    GLOAD_LDS16(Ab + (size_t)(t >> 2) * C + (t & 3) * 8,           &As[0][t * 8]);
    GLOAD_LDS16(Ab + (size_t)(64 + (t >> 2)) * C + (t & 3) * 8,    &As[0][(t + 256) * 8]);
    GLOAD_LDS16(Bb + (size_t)(t >> 2) * C + (t & 3) * 8,           &Bs[0][t * 8]);
    GLOAD_LDS16(Bb + (size_t)(64 + (t >> 2)) * C + (t & 3) * 8,    &Bs[0][(t + 256) * 8]);
  }
  __syncthreads();

  f32x4 acc[4][4] = {};
  int buf = 0;
  for (int kt = 0; kt < 16; kt++) {
    if (kt + 1 < 16) {
      int k0 = (kt + 1) * 32;
      GLOAD_LDS16(Ab + (size_t)(t >> 2) * C + k0 + (t & 3) * 8,        &As[buf ^ 1][t * 8]);
      GLOAD_LDS16(Ab + (size_t)(64 + (t >> 2)) * C + k0 + (t & 3) * 8, &As[buf ^ 1][(t + 256) * 8]);
      GLOAD_LDS16(Bb + (size_t)(t >> 2) * C + k0 + (t & 3) * 8,        &Bs[buf ^ 1][t * 8]);
      GLOAD_LDS16(Bb + (size_t)(64 + (t >> 2)) * C + k0 + (t & 3) * 8, &Bs[buf ^ 1][(t + 256) * 8]);
    }
    bf16x8 af[4], bfr[4];
    #pragma unroll
    for (int i = 0; i < 4; i++) af[i]  = *(const bf16x8*)&As[buf][(mw + i * 16 + lr) * 32 + lg * 8];
    #pragma unroll
    for (int i = 0; i < 4; i++) bfr[i] = *(const bf16x8*)&Bs[buf][(nw + i * 16 + lr) * 32 + lg * 8];
    #pragma unroll
    for (int mi = 0; mi < 4; mi++)
      #pragma unroll
      for (int ni = 0; ni < 4; ni++)
        acc[mi][ni] = MFMA16(af[mi], bfr[ni], acc[mi][ni]);
    __syncthreads();
    buf ^= 1;
  }

  #pragma unroll
  for (int mi = 0; mi < 4; mi++) {
    #pragma unroll
    for (int ni = 0; ni < 4; ni++) {
      #pragma unroll
      for (int r = 0; r < 4; r++) {
        int srow = m0 + mw + mi * 16 + lg * 4 + r;
        int c = n0 + nw + ni * 16 + lr;
        out[(size_t)srow * C + c] = x[(size_t)srow * C + c] + acc[mi][ni][r] + bo[c];
      }
    }
  }
}

extern "C" void kernel_launch(void* const* d_in, const int* in_sizes, int n_in,
                              void* d_out, int out_size, void* d_ws, size_t ws_size,
                              hipStream_t stream) {
  const float* x  = (const float*)d_in[0];
  const float* gs = (const float*)d_in[1];
  const float* gb = (const float*)d_in[2];
  const float* wq = (const float*)d_in[3];
  const float* bq = (const float*)d_in[4];
  const float* wk = (const float*)d_in[5];
  const float* bk = (const float*)d_in[6];
  const float* wv = (const float*)d_in[7];
  const float* bv = (const float*)d_in[8];
  const float* wo = (const float*)d_in[9];
  const float* bo = (const float*)d_in[10];

  char* ws = (char*)d_ws;
  ushort* h    = (ushort*)(ws);                    // 8 MB  [M][C] bf16 (dead after qkv -> reused as po1)
  ushort* wT   = (ushort*)(ws + 8388608);          // 2 MB  [2048][512] bf16 (wqT,wkT,wvT,woT)
  ushort* qb   = (ushort*)(ws + 10485760);         // 8 MB  [M][512] bf16 (dead after attn -> reused as final O)
  ushort* kb   = (ushort*)(ws + 18874368);         // 8 MB  [M][512] bf16
  ushort* vTb  = (ushort*)(ws + 27262976);         // 8 MB  [B][512][S] bf16 (transposed)
  ushort* po0  = (ushort*)(ws + 35651584);         // 8 MB  [NROWS][64] bf16 partial O half 0
  float2* st   = (float2*)(ws + 44040192);         // 512 B
  float*  pm   = (float*)(ws + 44041216);          // 512 KB [2][NROWS]
  float*  pl   = (float*)(ws + 44565504);          // 512 KB [2][NROWS]
  ushort* po1  = h;                                // overlay: h is dead after qkv_gemm
  ushort* ofin = qb;                               // overlay: q is dead after attn

  gn_stats_kernel<<<64, 256, 0, stream>>>(x, st);
  wtrans_kernel<<<dim3(64, 4), 256, 0, stream>>>(wq, wk, wv, wo, wT);
  gn_apply_kernel<<<2048, 256, 0, stream>>>(x, gs, gb, st, h);
  qkv_gemm_kernel<<<dim3(64, 12), 256, 0, stream>>>(h, wT, bq, bk, bv, qb, kb, vTb);
  attn_kernel<<<dim3(32, 16, 2), 256, 0, stream>>>(qb, kb, vTb, po0, po1, pm, pl);
  attn_combine_kernel<<<16384, 256, 0, stream>>>(po0, po1, pm, pl, ofin);
  oproj_gemm_kernel<<<dim3(64, 4), 256, 0, stream>>>(ofin, wT + 786432, x, bo, (float*)d_out);
}